// Round 4
// baseline (183.068 us; speedup 1.0000x reference)
//
#include <hip/hip_runtime.h>

#define BN_EPS 1e-5f

typedef short bf16x8 __attribute__((ext_vector_type(8)));
typedef float f32x4  __attribute__((ext_vector_type(4)));

static __device__ __forceinline__ unsigned short f2bf(float f) {
    union { float f; unsigned int u; } v; v.f = f;
    unsigned int u = v.u;
    unsigned int r = (u + 0x7FFFu + ((u >> 16) & 1u)) >> 16;   // round-to-nearest-even
    return (unsigned short)r;
}

// ---------------- fused prep kernel ----------------
// One launch does all prep:
//   blocks [0, nCvt)            : h fp32 -> hb bf16 (4 elems/thread)
//   blocks [nCvt, nCvt+128)     : W0 -> frag-linear W0sw (BN0 scale folded)
//   blocks [nCvt+128, nCvt+192) : W1 -> frag-linear W1sw (BN1 scale folded)
//   blocks [nCvt+192, nCvt+320) : folded biases b0f/b1f, w2f, b2f (1 wave/row)
__global__ __launch_bounds__(256) void k_prep(
        const float* __restrict__ h, unsigned short* __restrict__ hb, int n4, int nCvt,
        const float* __restrict__ W0, const float* __restrict__ b0,
        const float* __restrict__ W1, const float* __restrict__ b1,
        const float* __restrict__ W2, const float* __restrict__ b2,
        const float* __restrict__ g0, const float* __restrict__ be0,
        const float* __restrict__ m0, const float* __restrict__ v0,
        const float* __restrict__ g1, const float* __restrict__ be1,
        const float* __restrict__ m1, const float* __restrict__ v1,
        const float* __restrict__ g2, const float* __restrict__ be2,
        const float* __restrict__ m2, const float* __restrict__ v2,
        unsigned short* __restrict__ W0sw, unsigned short* __restrict__ W1sw,
        float* __restrict__ b0f, float* __restrict__ b1f,
        float* __restrict__ w2f, float* __restrict__ b2f) {
    const int b = blockIdx.x;
    const int tid = threadIdx.x;

    if (b < nCvt) {                       // ---- h -> bf16 ----
        int i = b * 256 + tid;
        if (i < n4) {
            float4 f = ((const float4*)h)[i];
            ushort4 o;
            o.x = f2bf(f.x); o.y = f2bf(f.y); o.z = f2bf(f.z); o.w = f2bf(f.w);
            ((ushort4*)hb)[i] = o;
        }
        return;
    }
    int br = b - nCvt;
    if (br < 128) {                        // ---- W0sw ----
        int t = br * 256 + tid;            // < 32768
        int j = t & 7, lane = (t >> 3) & 63, nt = (t >> 9) & 7, kb = t >> 12;
        int k = kb * 32 + (lane >> 4) * 8 + j;
        int n = nt * 16 + (lane & 15);
        float s = g0[k] * rsqrtf(v0[k] + BN_EPS);
        W0sw[t] = f2bf(W0[n * 256 + k] * s);
        return;
    }
    br -= 128;
    if (br < 64) {                         // ---- W1sw ----
        int t = br * 256 + tid;            // < 16384
        int j = t & 7, lane = (t >> 3) & 63, nt = (t >> 9) & 7, kb = t >> 12;
        int k = kb * 32 + (lane >> 4) * 8 + j;
        int n = nt * 16 + (lane & 15);
        float s = g1[k] * rsqrtf(v1[k] + BN_EPS);
        W1sw[t] = f2bf(W1[n * 128 + k] * s);
        return;
    }
    br -= 64;
    {                                      // ---- folded biases (row = br), wave 0 only ----
        if (tid >= 64) return;
        const int i = br, lane = tid;
        float s0 = 0.f;
#pragma unroll
        for (int c = 0; c < 4; c++) {
            int k = c * 64 + lane;
            float sc = g0[k] * rsqrtf(v0[k] + BN_EPS);
            s0 += W0[i * 256 + k] * (be0[k] - m0[k] * sc);
        }
        float s1 = 0.f;
#pragma unroll
        for (int c = 0; c < 2; c++) {
            int k = c * 64 + lane;
            float sc = g1[k] * rsqrtf(v1[k] + BN_EPS);
            s1 += W1[i * 128 + k] * (be1[k] - m1[k] * sc);
        }
        float s2 = 0.f;
        if (i == 0) {
#pragma unroll
            for (int c = 0; c < 2; c++) {
                int k = c * 64 + lane;
                float sc = g2[k] * rsqrtf(v2[k] + BN_EPS);
                s2 += W2[k] * (be2[k] - m2[k] * sc);
            }
        }
#pragma unroll
        for (int off = 1; off < 64; off <<= 1) {
            s0 += __shfl_xor(s0, off);
            s1 += __shfl_xor(s1, off);
            s2 += __shfl_xor(s2, off);
        }
        if (lane == 0) {
            b0f[i] = b0[i] + s0;
            b1f[i] = b1[i] + s1;
            w2f[i] = W2[i] * (g2[i] * rsqrtf(v2[i] + BN_EPS));
            if (i == 0) b2f[0] = b2[0] + s2;
        }
    }
}

// ---------------- main fused kernel: WEIGHT-STATIONARY ----------------
// Block = 4 waves. Wave w owns n-slice [32w, 32w+32) = nt {2w, 2w+1} and keeps
// its B-fragments of W0 (16 frags) + W1 (8 frags) in REGISTERS for the whole
// kernel. Grid-stride loop over 64-edge groups:
//   stage0: A = 32 gathered global bf16x8 (4 waves read SAME rows -> L1
//           broadcast), 16 MFMAs/kb over persistent B0.
//   epilogue: relu(x0+b0') -> shared x1S tile (frag-linear; wave w writes
//           exactly the kb1=w slice).  barrier.
//   stage1: A = 16 conflict-free ds_read_b128 from x1S, persistent B1.
//   stage2: per-wave partial dot over its 32 n -> pS, barrier, wave 0 reduces
//           4 partials/edge and stores 64 coalesced floats.
__global__ __launch_bounds__(256, 2) void k_main(
        const int* __restrict__ src, const int* __restrict__ dst,
        const unsigned short* __restrict__ hb,
        const unsigned short* __restrict__ W0sw, const unsigned short* __restrict__ W1sw,
        const float* __restrict__ b0f, const float* __restrict__ b1f,
        const float* __restrict__ w2f, const float* __restrict__ b2fp,
        float* __restrict__ out, int E, int nGroups) {
    __shared__ __align__(16) unsigned short x1S[4][4][64][8];  // [g][kb1][lane][j] 16 KB
    __shared__ float pS[4][64];                                // wave partials per edge

    const int tid  = threadIdx.x;
    const int wave = tid >> 6;
    const int lane = tid & 63;
    const int quad = lane >> 4;
    const int m    = lane & 15;

    // ---- persistent per-wave weight fragments (n-slice nt = 2*wave + h) ----
    bf16x8 B0[8][2], B1[4][2];
#pragma unroll
    for (int kb = 0; kb < 8; kb++)
#pragma unroll
        for (int hh = 0; hh < 2; hh++)
            B0[kb][hh] = *(const bf16x8*)(W0sw + ((kb * 8 + (wave * 2 + hh)) * 64 + lane) * 8);
#pragma unroll
    for (int kb = 0; kb < 4; kb++)
#pragma unroll
        for (int hh = 0; hh < 2; hh++)
            B1[kb][hh] = *(const bf16x8*)(W1sw + ((kb * 8 + (wave * 2 + hh)) * 64 + lane) * 8);

    float b0v[2], b1v[2], w2v[2];
#pragma unroll
    for (int hh = 0; hh < 2; hh++) {
        int n = (wave * 2 + hh) * 16 + m;
        b0v[hh] = b0f[n];
        b1v[hh] = b1f[n];
        w2v[hh] = w2f[n];
    }
    const float b2s = *b2fp;

    for (int gi = blockIdx.x; gi < nGroups; gi += gridDim.x) {
        const int eBase = gi * 64;

        int rS[4], rD[4];
#pragma unroll
        for (int g = 0; g < 4; g++) {
            int e = eBase + g * 16 + m;
            if (e >= E) e = E - 1;
            rS[g] = src[e];
            rD[g] = dst[e];
        }

        // ---- stage 0: [64 x 256] @ W0slice -> acc0[g][h] ----
        f32x4 acc0[4][2];
#pragma unroll
        for (int g = 0; g < 4; g++)
#pragma unroll
            for (int hh = 0; hh < 2; hh++) acc0[g][hh] = (f32x4){0.f, 0.f, 0.f, 0.f};

#pragma unroll
        for (int kb = 0; kb < 8; kb++) {
            bf16x8 a[4];
#pragma unroll
            for (int g = 0; g < 4; g++) {
                int row = (kb < 4) ? rS[g] : rD[g];
                a[g] = *(const bf16x8*)(hb + row * 128 + (kb & 3) * 32 + quad * 8);
            }
#pragma unroll
            for (int hh = 0; hh < 2; hh++)
#pragma unroll
                for (int g = 0; g < 4; g++)
                    acc0[g][hh] = __builtin_amdgcn_mfma_f32_16x16x32_bf16(a[g], B0[kb][hh], acc0[g][hh], 0, 0, 0);
        }

        // ---- epilogue 0: relu -> x1S (wave w writes kb1 = w slice) ----
#pragma unroll
        for (int g = 0; g < 4; g++) {
#pragma unroll
            for (int hh = 0; hh < 2; hh++) {
                int qp = (hh << 1) | (m >> 3);
                int j  = m & 7;
#pragma unroll
                for (int r = 0; r < 4; r++) {
                    float v = acc0[g][hh][r] + b0v[hh];
                    v = v > 0.f ? v : 0.f;
                    x1S[g][wave][qp * 16 + quad * 4 + r][j] = f2bf(v);
                }
            }
        }
        __syncthreads();

        // ---- stage 1: [64 x 128] @ W1slice -> acc1[g][h] ----
        f32x4 acc1[4][2];
#pragma unroll
        for (int g = 0; g < 4; g++)
#pragma unroll
            for (int hh = 0; hh < 2; hh++) acc1[g][hh] = (f32x4){0.f, 0.f, 0.f, 0.f};

#pragma unroll
        for (int kb = 0; kb < 4; kb++) {
            bf16x8 a[4];
#pragma unroll
            for (int g = 0; g < 4; g++)
                a[g] = *(const bf16x8*)&x1S[g][kb][lane][0];
#pragma unroll
            for (int hh = 0; hh < 2; hh++)
#pragma unroll
                for (int g = 0; g < 4; g++)
                    acc1[g][hh] = __builtin_amdgcn_mfma_f32_16x16x32_bf16(a[g], B1[kb][hh], acc1[g][hh], 0, 0, 0);
        }

        // ---- stage 2: per-wave partial dot over its 32 n ----
#pragma unroll
        for (int g = 0; g < 4; g++) {
            float s[4] = {0.f, 0.f, 0.f, 0.f};
#pragma unroll
            for (int hh = 0; hh < 2; hh++)
#pragma unroll
                for (int r = 0; r < 4; r++) {
                    float v = acc1[g][hh][r] + b1v[hh];
                    v = v > 0.f ? v : 0.f;
                    s[r] += v * w2v[hh];
                }
#pragma unroll
            for (int off = 1; off < 16; off <<= 1)
#pragma unroll
                for (int r = 0; r < 4; r++) s[r] += __shfl_xor(s[r], off, 16);
            if (m == 0) {
#pragma unroll
                for (int r = 0; r < 4; r++) pS[wave][g * 16 + quad * 4 + r] = s[r];
            }
        }
        __syncthreads();

        if (wave == 0) {
            int e = eBase + lane;
            if (e < E)
                out[e] = pS[0][lane] + pS[1][lane] + pS[2][lane] + pS[3][lane] + b2s;
        }
        // next iter's x1S writes are gated by this iteration's 2nd barrier:
        // every wave passed it only after finishing its stage-1 reads.
    }
}

// ---------------- launcher ----------------
extern "C" void kernel_launch(void* const* d_in, const int* in_sizes, int n_in,
                              void* d_out, int out_size, void* d_ws, size_t ws_size,
                              hipStream_t stream) {
    const float* h   = (const float*)d_in[0];
    const int*   src = (const int*)d_in[1];
    const int*   dst = (const int*)d_in[2];
    const float* W0  = (const float*)d_in[3];
    const float* b0  = (const float*)d_in[4];
    const float* W1  = (const float*)d_in[5];
    const float* b1  = (const float*)d_in[6];
    const float* W2  = (const float*)d_in[7];
    const float* b2  = (const float*)d_in[8];
    const float* g0  = (const float*)d_in[9];
    const float* be0 = (const float*)d_in[10];
    const float* g1  = (const float*)d_in[11];
    const float* be1 = (const float*)d_in[12];
    const float* g2  = (const float*)d_in[13];
    const float* be2 = (const float*)d_in[14];
    const float* m0  = (const float*)d_in[15];
    const float* v0  = (const float*)d_in[16];
    const float* m1  = (const float*)d_in[17];
    const float* v1  = (const float*)d_in[18];
    const float* m2  = (const float*)d_in[19];
    const float* v2  = (const float*)d_in[20];
    float* out = (float*)d_out;

    const int hsz = in_sizes[0];          // N*128
    const int E   = in_sizes[1];

    char* ws = (char*)d_ws;
    size_t off = (size_t)hsz * 2;         // hb bytes
    off = (off + 255) & ~(size_t)255;
    unsigned short* hb   = (unsigned short*)ws;
    unsigned short* W0sw = (unsigned short*)(ws + off);  off += 65536;
    unsigned short* W1sw = (unsigned short*)(ws + off);  off += 32768;
    float* b0f = (float*)(ws + off);  off += 512;
    float* b1f = (float*)(ws + off);  off += 512;
    float* w2f = (float*)(ws + off);  off += 512;
    float* b2f = (float*)(ws + off);  off += 16;

    int n4   = hsz / 4;
    int nCvt = (n4 + 255) / 256;
    int prepBlocks = nCvt + 128 + 64 + 128;
    k_prep<<<prepBlocks, 256, 0, stream>>>(h, hb, n4, nCvt,
                                           W0, b0, W1, b1, W2, b2,
                                           g0, be0, m0, v0, g1, be1, m1, v1,
                                           g2, be2, m2, v2,
                                           W0sw, W1sw, b0f, b1f, w2f, b2f);

    int nGroups = (E + 63) / 64;
    int nBlocks = nGroups < 512 ? nGroups : 512;
    k_main<<<nBlocks, 256, 0, stream>>>(src, dst, hb, W0sw, W1sw,
                                        b0f, b1f, w2f, b2f, out, E, nGroups);
}

// Round 5
// 145.272 us; speedup vs baseline: 1.2602x; 1.2602x over previous
//
#include <hip/hip_runtime.h>

#define BN_EPS 1e-5f

typedef short bf16x8 __attribute__((ext_vector_type(8)));
typedef float f32x4  __attribute__((ext_vector_type(4)));

static __device__ __forceinline__ unsigned short f2bf(float f) {
    union { float f; unsigned int u; } v; v.f = f;
    unsigned int u = v.u;
    unsigned int r = (u + 0x7FFFu + ((u >> 16) & 1u)) >> 16;   // round-to-nearest-even
    return (unsigned short)r;
}

// ---------------- fused prep kernel (unchanged from R4) ----------------
__global__ __launch_bounds__(256) void k_prep(
        const float* __restrict__ h, unsigned short* __restrict__ hb, int n4, int nCvt,
        const float* __restrict__ W0, const float* __restrict__ b0,
        const float* __restrict__ W1, const float* __restrict__ b1,
        const float* __restrict__ W2, const float* __restrict__ b2,
        const float* __restrict__ g0, const float* __restrict__ be0,
        const float* __restrict__ m0, const float* __restrict__ v0,
        const float* __restrict__ g1, const float* __restrict__ be1,
        const float* __restrict__ m1, const float* __restrict__ v1,
        const float* __restrict__ g2, const float* __restrict__ be2,
        const float* __restrict__ m2, const float* __restrict__ v2,
        unsigned short* __restrict__ W0sw, unsigned short* __restrict__ W1sw,
        float* __restrict__ b0f, float* __restrict__ b1f,
        float* __restrict__ w2f, float* __restrict__ b2f) {
    const int b = blockIdx.x;
    const int tid = threadIdx.x;

    if (b < nCvt) {                       // ---- h -> bf16 ----
        int i = b * 256 + tid;
        if (i < n4) {
            float4 f = ((const float4*)h)[i];
            ushort4 o;
            o.x = f2bf(f.x); o.y = f2bf(f.y); o.z = f2bf(f.z); o.w = f2bf(f.w);
            ((ushort4*)hb)[i] = o;
        }
        return;
    }
    int br = b - nCvt;
    if (br < 128) {                        // ---- W0sw ----
        int t = br * 256 + tid;
        int j = t & 7, lane = (t >> 3) & 63, nt = (t >> 9) & 7, kb = t >> 12;
        int k = kb * 32 + (lane >> 4) * 8 + j;
        int n = nt * 16 + (lane & 15);
        float s = g0[k] * rsqrtf(v0[k] + BN_EPS);
        W0sw[t] = f2bf(W0[n * 256 + k] * s);
        return;
    }
    br -= 128;
    if (br < 64) {                         // ---- W1sw ----
        int t = br * 256 + tid;
        int j = t & 7, lane = (t >> 3) & 63, nt = (t >> 9) & 7, kb = t >> 12;
        int k = kb * 32 + (lane >> 4) * 8 + j;
        int n = nt * 16 + (lane & 15);
        float s = g1[k] * rsqrtf(v1[k] + BN_EPS);
        W1sw[t] = f2bf(W1[n * 128 + k] * s);
        return;
    }
    br -= 64;
    {                                      // ---- folded biases (row = br) ----
        if (tid >= 64) return;
        const int i = br, lane = tid;
        float s0 = 0.f;
#pragma unroll
        for (int c = 0; c < 4; c++) {
            int k = c * 64 + lane;
            float sc = g0[k] * rsqrtf(v0[k] + BN_EPS);
            s0 += W0[i * 256 + k] * (be0[k] - m0[k] * sc);
        }
        float s1 = 0.f;
#pragma unroll
        for (int c = 0; c < 2; c++) {
            int k = c * 64 + lane;
            float sc = g1[k] * rsqrtf(v1[k] + BN_EPS);
            s1 += W1[i * 128 + k] * (be1[k] - m1[k] * sc);
        }
        float s2 = 0.f;
        if (i == 0) {
#pragma unroll
            for (int c = 0; c < 2; c++) {
                int k = c * 64 + lane;
                float sc = g2[k] * rsqrtf(v2[k] + BN_EPS);
                s2 += W2[k] * (be2[k] - m2[k] * sc);
            }
        }
#pragma unroll
        for (int off = 1; off < 64; off <<= 1) {
            s0 += __shfl_xor(s0, off);
            s1 += __shfl_xor(s1, off);
            s2 += __shfl_xor(s2, off);
        }
        if (lane == 0) {
            b0f[i] = b0[i] + s0;
            b1f[i] = b1[i] + s1;
            w2f[i] = W2[i] * (g2[i] * rsqrtf(v2[i] + BN_EPS));
            if (i == 0) b2f[0] = b2[0] + s2;
        }
    }
}

// ---------------- main kernel: LDS-DMA gather + weight-stationary ----------------
// Block = 4 waves, 64 edges/group, grid-stride. Wave w owns n-slice [32w,32w+32)
// (B-frags persistent in regs) and gathers the g=w A-chunk via global_load_lds
// (per-lane global addr -> LDS base + lane*16 == A-frag layout, zero VGPR cost).
// Pipeline per group: barrier(a) [own DMA retired; pS visible] -> store prev out
// -> prefetch next indices -> stage0 (ds_read A + MFMA) -> x1 epilogue ->
// barrier(b) -> issue next group's DMA gather -> stage1 -> stage2 partials -> pS.
__global__ __launch_bounds__(256, 2) void k_main(
        const int* __restrict__ src, const int* __restrict__ dst,
        const unsigned short* __restrict__ hb,
        const unsigned short* __restrict__ W0sw, const unsigned short* __restrict__ W1sw,
        const float* __restrict__ b0f, const float* __restrict__ b1f,
        const float* __restrict__ w2f, const float* __restrict__ b2fp,
        float* __restrict__ out, int E, int nGroups) {
    // A: [g(4)][half(2)][kb4(4)][lane(64)][8 bf16] = 32 KB
    __shared__ __align__(16) unsigned short Abuf[4 * 2 * 4 * 64 * 8];
    __shared__ __align__(16) unsigned short x1S[4][4][64][8];   // 16 KB
    __shared__ float pS[4][64];                                 // 1 KB

    const int tid  = threadIdx.x;
    const int wave = tid >> 6;
    const int lane = tid & 63;
    const int quad = lane >> 4;
    const int m    = lane & 15;

    // ---- persistent per-wave weight fragments (nt = 2*wave + hh) ----
    bf16x8 B0[8][2], B1[4][2];
#pragma unroll
    for (int kb = 0; kb < 8; kb++)
#pragma unroll
        for (int hh = 0; hh < 2; hh++)
            B0[kb][hh] = *(const bf16x8*)(W0sw + ((kb * 8 + (wave * 2 + hh)) * 64 + lane) * 8);
#pragma unroll
    for (int kb = 0; kb < 4; kb++)
#pragma unroll
        for (int hh = 0; hh < 2; hh++)
            B1[kb][hh] = *(const bf16x8*)(W1sw + ((kb * 8 + (wave * 2 + hh)) * 64 + lane) * 8);

    float b0v[2], b1v[2], w2v[2];
#pragma unroll
    for (int hh = 0; hh < 2; hh++) {
        int n = (wave * 2 + hh) * 16 + m;
        b0v[hh] = b0f[n];
        b1v[hh] = b1f[n];
        w2v[hh] = w2f[n];
    }
    const float b2s = *b2fp;
    const int stride = gridDim.x;

    // ---- prologue: gather group blockIdx.x ----
    int gi = blockIdx.x;
    int rSn, rDn;
    {
        int e = gi * 64 + wave * 16 + m;
        if (e >= E) e = E - 1;
        rSn = src[e];
        rDn = dst[e];
#pragma unroll
        for (int half = 0; half < 2; half++) {
            int row = half ? rDn : rSn;
#pragma unroll
            for (int kb4 = 0; kb4 < 4; kb4++) {
                const unsigned short* gp = hb + (size_t)row * 128 + kb4 * 32 + quad * 8;
                unsigned short* lp = Abuf + ((wave * 2 + half) * 4 + kb4) * 512 + lane * 8;
                __builtin_amdgcn_global_load_lds(
                    (const __attribute__((address_space(1))) void*)gp,
                    (__attribute__((address_space(3))) void*)lp, 16, 0, 0);
            }
        }
    }

    int prevE = -1;
    for (; gi < nGroups; gi += stride) {
        __syncthreads();   // (a) own DMA retired -> A[gi] fully visible; pS[prev] visible

        if (prevE >= 0 && wave == 0) {
            int e = prevE + lane;
            if (e < E)
                out[e] = pS[0][lane] + pS[1][lane] + pS[2][lane] + pS[3][lane] + b2s;
        }

        // prefetch next group's indices (latency hidden under stage0)
        int nextGi = gi + stride;
        {
            int en = (nextGi < nGroups ? nextGi : gi) * 64 + wave * 16 + m;
            if (en >= E) en = E - 1;
            rSn = src[en];
            rDn = dst[en];
        }

        // ---- stage 0: [64 x 256] @ W0slice ----
        f32x4 acc0[4][2];
#pragma unroll
        for (int g = 0; g < 4; g++)
#pragma unroll
            for (int hh = 0; hh < 2; hh++) acc0[g][hh] = (f32x4){0.f, 0.f, 0.f, 0.f};

#pragma unroll
        for (int kb = 0; kb < 8; kb++) {
            bf16x8 a[4];
#pragma unroll
            for (int g = 0; g < 4; g++)
                a[g] = *(const bf16x8*)(Abuf + ((g * 2 + (kb >> 2)) * 4 + (kb & 3)) * 512 + lane * 8);
#pragma unroll
            for (int hh = 0; hh < 2; hh++)
#pragma unroll
                for (int g = 0; g < 4; g++)
                    acc0[g][hh] = __builtin_amdgcn_mfma_f32_16x16x32_bf16(a[g], B0[kb][hh], acc0[g][hh], 0, 0, 0);
        }

        // ---- epilogue 0: relu -> x1S (wave w writes kb1 = w slice) ----
#pragma unroll
        for (int g = 0; g < 4; g++) {
#pragma unroll
            for (int hh = 0; hh < 2; hh++) {
                int qp = (hh << 1) | (m >> 3);
                int j  = m & 7;
#pragma unroll
                for (int r = 0; r < 4; r++) {
                    float v = acc0[g][hh][r] + b0v[hh];
                    v = v > 0.f ? v : 0.f;
                    x1S[g][wave][qp * 16 + quad * 4 + r][j] = f2bf(v);
                }
            }
        }
        __syncthreads();   // (b) x1 visible; all stage-0 A reads done

        // ---- issue next group's DMA gather (overwrites Abuf, safe after (b)) ----
        if (nextGi < nGroups) {
#pragma unroll
            for (int half = 0; half < 2; half++) {
                int row = half ? rDn : rSn;
#pragma unroll
                for (int kb4 = 0; kb4 < 4; kb4++) {
                    const unsigned short* gp = hb + (size_t)row * 128 + kb4 * 32 + quad * 8;
                    unsigned short* lp = Abuf + ((wave * 2 + half) * 4 + kb4) * 512 + lane * 8;
                    __builtin_amdgcn_global_load_lds(
                        (const __attribute__((address_space(1))) void*)gp,
                        (__attribute__((address_space(3))) void*)lp, 16, 0, 0);
                }
            }
        }

        // ---- stage 1: [64 x 128] @ W1slice ----
        f32x4 acc1[4][2];
#pragma unroll
        for (int g = 0; g < 4; g++)
#pragma unroll
            for (int hh = 0; hh < 2; hh++) acc1[g][hh] = (f32x4){0.f, 0.f, 0.f, 0.f};

#pragma unroll
        for (int kb = 0; kb < 4; kb++) {
            bf16x8 a[4];
#pragma unroll
            for (int g = 0; g < 4; g++)
                a[g] = *(const bf16x8*)&x1S[g][kb][lane][0];
#pragma unroll
            for (int hh = 0; hh < 2; hh++)
#pragma unroll
                for (int g = 0; g < 4; g++)
                    acc1[g][hh] = __builtin_amdgcn_mfma_f32_16x16x32_bf16(a[g], B1[kb][hh], acc1[g][hh], 0, 0, 0);
        }

        // ---- stage 2: per-wave partial dot -> pS (read next iter after (a)) ----
#pragma unroll
        for (int g = 0; g < 4; g++) {
            float s[4] = {0.f, 0.f, 0.f, 0.f};
#pragma unroll
            for (int hh = 0; hh < 2; hh++)
#pragma unroll
                for (int r = 0; r < 4; r++) {
                    float v = acc1[g][hh][r] + b1v[hh];
                    v = v > 0.f ? v : 0.f;
                    s[r] += v * w2v[hh];
                }
#pragma unroll
            for (int off = 1; off < 16; off <<= 1)
#pragma unroll
                for (int r = 0; r < 4; r++) s[r] += __shfl_xor(s[r], off, 16);
            if (m == 0) {
#pragma unroll
                for (int r = 0; r < 4; r++) pS[wave][g * 16 + quad * 4 + r] = s[r];
            }
        }
        prevE = gi * 64;
    }

    __syncthreads();
    if (prevE >= 0 && wave == 0) {
        int e = prevE + lane;
        if (e < E)
            out[e] = pS[0][lane] + pS[1][lane] + pS[2][lane] + pS[3][lane] + b2s;
    }
}

// ---------------- launcher ----------------
extern "C" void kernel_launch(void* const* d_in, const int* in_sizes, int n_in,
                              void* d_out, int out_size, void* d_ws, size_t ws_size,
                              hipStream_t stream) {
    const float* h   = (const float*)d_in[0];
    const int*   src = (const int*)d_in[1];
    const int*   dst = (const int*)d_in[2];
    const float* W0  = (const float*)d_in[3];
    const float* b0  = (const float*)d_in[4];
    const float* W1  = (const float*)d_in[5];
    const float* b1  = (const float*)d_in[6];
    const float* W2  = (const float*)d_in[7];
    const float* b2  = (const float*)d_in[8];
    const float* g0  = (const float*)d_in[9];
    const float* be0 = (const float*)d_in[10];
    const float* g1  = (const float*)d_in[11];
    const float* be1 = (const float*)d_in[12];
    const float* g2  = (const float*)d_in[13];
    const float* be2 = (const float*)d_in[14];
    const float* m0  = (const float*)d_in[15];
    const float* v0  = (const float*)d_in[16];
    const float* m1  = (const float*)d_in[17];
    const float* v1  = (const float*)d_in[18];
    const float* m2  = (const float*)d_in[19];
    const float* v2  = (const float*)d_in[20];
    float* out = (float*)d_out;

    const int hsz = in_sizes[0];          // N*128
    const int E   = in_sizes[1];

    char* ws = (char*)d_ws;
    size_t off = (size_t)hsz * 2;         // hb bytes
    off = (off + 255) & ~(size_t)255;
    unsigned short* hb   = (unsigned short*)ws;
    unsigned short* W0sw = (unsigned short*)(ws + off);  off += 65536;
    unsigned short* W1sw = (unsigned short*)(ws + off);  off += 32768;
    float* b0f = (float*)(ws + off);  off += 512;
    float* b1f = (float*)(ws + off);  off += 512;
    float* w2f = (float*)(ws + off);  off += 512;
    float* b2f = (float*)(ws + off);  off += 16;

    int n4   = hsz / 4;
    int nCvt = (n4 + 255) / 256;
    int prepBlocks = nCvt + 128 + 64 + 128;
    k_prep<<<prepBlocks, 256, 0, stream>>>(h, hb, n4, nCvt,
                                           W0, b0, W1, b1, W2, b2,
                                           g0, be0, m0, v0, g1, be1, m1, v1,
                                           g2, be2, m2, v2,
                                           W0sw, W1sw, b0f, b1f, w2f, b2f);

    int nGroups = (E + 63) / 64;
    int nBlocks = nGroups < 512 ? nGroups : 512;
    k_main<<<nBlocks, 256, 0, stream>>>(src, dst, hb, W0sw, W1sw,
                                        b0f, b1f, w2f, b2f, out, E, nGroups);
}

// Round 6
// 143.579 us; speedup vs baseline: 1.2750x; 1.0118x over previous
//
#include <hip/hip_runtime.h>
#include <hip/hip_bf16.h>

#define BN_EPS 1e-5f

typedef short bf16x8 __attribute__((ext_vector_type(8)));
typedef float f32x4  __attribute__((ext_vector_type(4)));

static __device__ __forceinline__ unsigned short f2bf(float f) {
    union { float f; unsigned int u; } v; v.f = f;
    unsigned int u = v.u;
    unsigned int r = (u + 0x7FFFu + ((u >> 16) & 1u)) >> 16;   // round-to-nearest-even
    return (unsigned short)r;
}

// hot-path: single HW cvt (RNE) instead of 4 integer ops
static __device__ __forceinline__ unsigned short f2bf_hw(float f) {
    __hip_bfloat16 b = __float2bfloat16(f);
    union { __hip_bfloat16 b; unsigned short u; } v; v.b = b;
    return v.u;
}

// ---------------- fused prep kernel ----------------
__global__ __launch_bounds__(256) void k_prep(
        const float* __restrict__ h, unsigned short* __restrict__ hb, int n4, int nCvt,
        const float* __restrict__ W0, const float* __restrict__ b0,
        const float* __restrict__ W1, const float* __restrict__ b1,
        const float* __restrict__ W2, const float* __restrict__ b2,
        const float* __restrict__ g0, const float* __restrict__ be0,
        const float* __restrict__ m0, const float* __restrict__ v0,
        const float* __restrict__ g1, const float* __restrict__ be1,
        const float* __restrict__ m1, const float* __restrict__ v1,
        const float* __restrict__ g2, const float* __restrict__ be2,
        const float* __restrict__ m2, const float* __restrict__ v2,
        unsigned short* __restrict__ W0sw, unsigned short* __restrict__ W1sw,
        float* __restrict__ b0f, float* __restrict__ b1f,
        float* __restrict__ w2f, float* __restrict__ b2f) {
    const int b = blockIdx.x;
    const int tid = threadIdx.x;

    if (b < nCvt) {                       // ---- h -> bf16 ----
        int i = b * 256 + tid;
        if (i < n4) {
            float4 f = ((const float4*)h)[i];
            ushort4 o;
            o.x = f2bf(f.x); o.y = f2bf(f.y); o.z = f2bf(f.z); o.w = f2bf(f.w);
            ((ushort4*)hb)[i] = o;
        }
        return;
    }
    int br = b - nCvt;
    if (br < 128) {                        // ---- W0sw ----
        int t = br * 256 + tid;
        int j = t & 7, lane = (t >> 3) & 63, nt = (t >> 9) & 7, kb = t >> 12;
        int k = kb * 32 + (lane >> 4) * 8 + j;
        int n = nt * 16 + (lane & 15);
        float s = g0[k] * rsqrtf(v0[k] + BN_EPS);
        W0sw[t] = f2bf(W0[n * 256 + k] * s);
        return;
    }
    br -= 128;
    if (br < 64) {                         // ---- W1sw ----
        int t = br * 256 + tid;
        int j = t & 7, lane = (t >> 3) & 63, nt = (t >> 9) & 7, kb = t >> 12;
        int k = kb * 32 + (lane >> 4) * 8 + j;
        int n = nt * 16 + (lane & 15);
        float s = g1[k] * rsqrtf(v1[k] + BN_EPS);
        W1sw[t] = f2bf(W1[n * 128 + k] * s);
        return;
    }
    br -= 64;
    {                                      // ---- folded biases (row = br) ----
        if (tid >= 64) return;
        const int i = br, lane = tid;
        float s0 = 0.f;
#pragma unroll
        for (int c = 0; c < 4; c++) {
            int k = c * 64 + lane;
            float sc = g0[k] * rsqrtf(v0[k] + BN_EPS);
            s0 += W0[i * 256 + k] * (be0[k] - m0[k] * sc);
        }
        float s1 = 0.f;
#pragma unroll
        for (int c = 0; c < 2; c++) {
            int k = c * 64 + lane;
            float sc = g1[k] * rsqrtf(v1[k] + BN_EPS);
            s1 += W1[i * 128 + k] * (be1[k] - m1[k] * sc);
        }
        float s2 = 0.f;
        if (i == 0) {
#pragma unroll
            for (int c = 0; c < 2; c++) {
                int k = c * 64 + lane;
                float sc = g2[k] * rsqrtf(v2[k] + BN_EPS);
                s2 += W2[k] * (be2[k] - m2[k] * sc);
            }
        }
#pragma unroll
        for (int off = 1; off < 64; off <<= 1) {
            s0 += __shfl_xor(s0, off);
            s1 += __shfl_xor(s1, off);
            s2 += __shfl_xor(s2, off);
        }
        if (lane == 0) {
            b0f[i] = b0[i] + s0;
            b1f[i] = b1[i] + s1;
            w2f[i] = W2[i] * (g2[i] * rsqrtf(v2[i] + BN_EPS));
            if (i == 0) b2f[0] = b2[0] + s2;
        }
    }
}

// ---------------- main kernel: LDS-DMA gather + weight-stationary ----------------
// Block = 4 waves, 64 edges/group, grid-stride, 3 blocks/CU (grid 768, LDS 49 KB,
// VGPR<=170 via launch_bounds(256,3)). Wave w owns n-slice [32w,32w+32) with
// B-frags persistent in regs; A gathered via global_load_lds (zero VGPR cost).
// Per group: barrier(a) [DMA retired, pS visible] -> store prev out -> prefetch
// next indices -> stage0 -> x1 epilogue -> barrier(b) -> issue next DMA ->
// stage1 -> stage2 partials -> pS.
__global__ __launch_bounds__(256, 3) void k_main(
        const int* __restrict__ src, const int* __restrict__ dst,
        const unsigned short* __restrict__ hb,
        const unsigned short* __restrict__ W0sw, const unsigned short* __restrict__ W1sw,
        const float* __restrict__ b0f, const float* __restrict__ b1f,
        const float* __restrict__ w2f, const float* __restrict__ b2fp,
        float* __restrict__ out, int E, int nGroups) {
    // A: [g(4)][half(2)][kb4(4)][lane(64)][8 bf16] = 32 KB
    __shared__ __align__(16) unsigned short Abuf[4 * 2 * 4 * 64 * 8];
    __shared__ __align__(16) unsigned short x1S[4][4][64][8];   // 16 KB
    __shared__ float pS[4][64];                                 // 1 KB

    const int tid  = threadIdx.x;
    const int wave = tid >> 6;
    const int lane = tid & 63;
    const int quad = lane >> 4;
    const int m    = lane & 15;

    // ---- persistent per-wave weight fragments (nt = 2*wave + hh) ----
    bf16x8 B0[8][2], B1[4][2];
#pragma unroll
    for (int kb = 0; kb < 8; kb++)
#pragma unroll
        for (int hh = 0; hh < 2; hh++)
            B0[kb][hh] = *(const bf16x8*)(W0sw + ((kb * 8 + (wave * 2 + hh)) * 64 + lane) * 8);
#pragma unroll
    for (int kb = 0; kb < 4; kb++)
#pragma unroll
        for (int hh = 0; hh < 2; hh++)
            B1[kb][hh] = *(const bf16x8*)(W1sw + ((kb * 8 + (wave * 2 + hh)) * 64 + lane) * 8);

    float b0v[2], b1v[2], w2v[2];
#pragma unroll
    for (int hh = 0; hh < 2; hh++) {
        int n = (wave * 2 + hh) * 16 + m;
        b0v[hh] = b0f[n];
        b1v[hh] = b1f[n];
        w2v[hh] = w2f[n];
    }
    const float b2s = *b2fp;
    const int stride = gridDim.x;

    // ---- prologue: gather group blockIdx.x ----
    int gi = blockIdx.x;
    int rSn, rDn;
    {
        int e = gi * 64 + wave * 16 + m;
        if (e >= E) e = E - 1;
        rSn = src[e];
        rDn = dst[e];
#pragma unroll
        for (int half = 0; half < 2; half++) {
            int row = half ? rDn : rSn;
#pragma unroll
            for (int kb4 = 0; kb4 < 4; kb4++) {
                const unsigned short* gp = hb + (size_t)row * 128 + kb4 * 32 + quad * 8;
                unsigned short* lp = Abuf + ((wave * 2 + half) * 4 + kb4) * 512 + lane * 8;
                __builtin_amdgcn_global_load_lds(
                    (const __attribute__((address_space(1))) void*)gp,
                    (__attribute__((address_space(3))) void*)lp, 16, 0, 0);
            }
        }
    }

    int prevE = -1;
    for (; gi < nGroups; gi += stride) {
        __syncthreads();   // (a) own DMA retired; pS[prev] visible

        if (prevE >= 0 && wave == 0) {
            int e = prevE + lane;
            if (e < E)
                out[e] = pS[0][lane] + pS[1][lane] + pS[2][lane] + pS[3][lane] + b2s;
        }

        // prefetch next group's indices (latency hidden under stage0)
        int nextGi = gi + stride;
        {
            int en = (nextGi < nGroups ? nextGi : gi) * 64 + wave * 16 + m;
            if (en >= E) en = E - 1;
            rSn = src[en];
            rDn = dst[en];
        }

        // ---- stage 0: [64 x 256] @ W0slice ----
        f32x4 acc0[4][2];
#pragma unroll
        for (int g = 0; g < 4; g++)
#pragma unroll
            for (int hh = 0; hh < 2; hh++) acc0[g][hh] = (f32x4){0.f, 0.f, 0.f, 0.f};

#pragma unroll
        for (int kb = 0; kb < 8; kb++) {
            bf16x8 a[4];
#pragma unroll
            for (int g = 0; g < 4; g++)
                a[g] = *(const bf16x8*)(Abuf + ((g * 2 + (kb >> 2)) * 4 + (kb & 3)) * 512 + lane * 8);
#pragma unroll
            for (int hh = 0; hh < 2; hh++)
#pragma unroll
                for (int g = 0; g < 4; g++)
                    acc0[g][hh] = __builtin_amdgcn_mfma_f32_16x16x32_bf16(a[g], B0[kb][hh], acc0[g][hh], 0, 0, 0);
        }

        // ---- epilogue 0: relu -> x1S (wave w writes kb1 = w slice) ----
#pragma unroll
        for (int g = 0; g < 4; g++) {
#pragma unroll
            for (int hh = 0; hh < 2; hh++) {
                int qp = (hh << 1) | (m >> 3);
                int j  = m & 7;
#pragma unroll
                for (int r = 0; r < 4; r++) {
                    float v = acc0[g][hh][r] + b0v[hh];
                    v = v > 0.f ? v : 0.f;
                    x1S[g][wave][qp * 16 + quad * 4 + r][j] = f2bf_hw(v);
                }
            }
        }
        __syncthreads();   // (b) x1 visible; stage-0 A reads done

        // ---- issue next group's DMA gather (overwrites Abuf, safe after (b)) ----
        if (nextGi < nGroups) {
#pragma unroll
            for (int half = 0; half < 2; half++) {
                int row = half ? rDn : rSn;
#pragma unroll
                for (int kb4 = 0; kb4 < 4; kb4++) {
                    const unsigned short* gp = hb + (size_t)row * 128 + kb4 * 32 + quad * 8;
                    unsigned short* lp = Abuf + ((wave * 2 + half) * 4 + kb4) * 512 + lane * 8;
                    __builtin_amdgcn_global_load_lds(
                        (const __attribute__((address_space(1))) void*)gp,
                        (__attribute__((address_space(3))) void*)lp, 16, 0, 0);
                }
            }
        }

        // ---- stage 1: [64 x 128] @ W1slice ----
        f32x4 acc1[4][2];
#pragma unroll
        for (int g = 0; g < 4; g++)
#pragma unroll
            for (int hh = 0; hh < 2; hh++) acc1[g][hh] = (f32x4){0.f, 0.f, 0.f, 0.f};

#pragma unroll
        for (int kb = 0; kb < 4; kb++) {
            bf16x8 a[4];
#pragma unroll
            for (int g = 0; g < 4; g++)
                a[g] = *(const bf16x8*)&x1S[g][kb][lane][0];
#pragma unroll
            for (int hh = 0; hh < 2; hh++)
#pragma unroll
                for (int g = 0; g < 4; g++)
                    acc1[g][hh] = __builtin_amdgcn_mfma_f32_16x16x32_bf16(a[g], B1[kb][hh], acc1[g][hh], 0, 0, 0);
        }

        // ---- stage 2: per-wave partial dot -> pS ----
#pragma unroll
        for (int g = 0; g < 4; g++) {
            float s[4] = {0.f, 0.f, 0.f, 0.f};
#pragma unroll
            for (int hh = 0; hh < 2; hh++)
#pragma unroll
                for (int r = 0; r < 4; r++) {
                    float v = acc1[g][hh][r] + b1v[hh];
                    v = v > 0.f ? v : 0.f;
                    s[r] += v * w2v[hh];
                }
#pragma unroll
            for (int off = 1; off < 16; off <<= 1)
#pragma unroll
                for (int r = 0; r < 4; r++) s[r] += __shfl_xor(s[r], off, 16);
            if (m == 0) {
#pragma unroll
                for (int r = 0; r < 4; r++) pS[wave][g * 16 + quad * 4 + r] = s[r];
            }
        }
        prevE = gi * 64;
    }

    __syncthreads();
    if (prevE >= 0 && wave == 0) {
        int e = prevE + lane;
        if (e < E)
            out[e] = pS[0][lane] + pS[1][lane] + pS[2][lane] + pS[3][lane] + b2s;
    }
}

// ---------------- launcher ----------------
extern "C" void kernel_launch(void* const* d_in, const int* in_sizes, int n_in,
                              void* d_out, int out_size, void* d_ws, size_t ws_size,
                              hipStream_t stream) {
    const float* h   = (const float*)d_in[0];
    const int*   src = (const int*)d_in[1];
    const int*   dst = (const int*)d_in[2];
    const float* W0  = (const float*)d_in[3];
    const float* b0  = (const float*)d_in[4];
    const float* W1  = (const float*)d_in[5];
    const float* b1  = (const float*)d_in[6];
    const float* W2  = (const float*)d_in[7];
    const float* b2  = (const float*)d_in[8];
    const float* g0  = (const float*)d_in[9];
    const float* be0 = (const float*)d_in[10];
    const float* g1  = (const float*)d_in[11];
    const float* be1 = (const float*)d_in[12];
    const float* g2  = (const float*)d_in[13];
    const float* be2 = (const float*)d_in[14];
    const float* m0  = (const float*)d_in[15];
    const float* v0  = (const float*)d_in[16];
    const float* m1  = (const float*)d_in[17];
    const float* v1  = (const float*)d_in[18];
    const float* m2  = (const float*)d_in[19];
    const float* v2  = (const float*)d_in[20];
    float* out = (float*)d_out;

    const int hsz = in_sizes[0];          // N*128
    const int E   = in_sizes[1];

    char* ws = (char*)d_ws;
    size_t off = (size_t)hsz * 2;         // hb bytes
    off = (off + 255) & ~(size_t)255;
    unsigned short* hb   = (unsigned short*)ws;
    unsigned short* W0sw = (unsigned short*)(ws + off);  off += 65536;
    unsigned short* W1sw = (unsigned short*)(ws + off);  off += 32768;
    float* b0f = (float*)(ws + off);  off += 512;
    float* b1f = (float*)(ws + off);  off += 512;
    float* w2f = (float*)(ws + off);  off += 512;
    float* b2f = (float*)(ws + off);  off += 16;

    int n4   = hsz / 4;
    int nCvt = (n4 + 255) / 256;
    int prepBlocks = nCvt + 128 + 64 + 128;
    k_prep<<<prepBlocks, 256, 0, stream>>>(h, hb, n4, nCvt,
                                           W0, b0, W1, b1, W2, b2,
                                           g0, be0, m0, v0, g1, be1, m1, v1,
                                           g2, be2, m2, v2,
                                           W0sw, W1sw, b0f, b1f, w2f, b2f);

    int nGroups = (E + 63) / 64;
    int nBlocks = nGroups < 768 ? nGroups : 768;   // 3 blocks/CU (LDS 49 KB, VGPR<=170)
    k_main<<<nBlocks, 256, 0, stream>>>(src, dst, hb, W0sw, W1sw,
                                        b0f, b1f, w2f, b2f, out, E, nGroups);
}